// Round 1
// baseline (234.186 us; speedup 1.0000x reference)
//
#include <hip/hip_runtime.h>

#define KK 50000
#define EE 128
#define HH 512
#define DIN 513

typedef short bh8 __attribute__((ext_vector_type(8)));
typedef float fx16 __attribute__((ext_vector_type(16)));

__device__ __forceinline__ short f2b(float f) {
  unsigned u = __float_as_uint(f);
  u = u + 0x7fffu + ((u >> 16) & 1u);
  return (short)(u >> 16);
}
__device__ __forceinline__ float b2f(short b) {
  return __uint_as_float(((unsigned)(unsigned short)b) << 16);
}
__device__ __forceinline__ float sigm(float x) { return 1.f / (1.f + __expf(-x)); }
__device__ __forceinline__ float tanh_(float x) {
  float ax = fabsf(x);
  float e = __expf(-2.f * ax);
  float t = (1.f - e) / (1.f + e);
  return copysignf(t, x);
}

// alpha[r] = dot(km[r,:], o_e) ; 16 lanes per row, 8 f32 each
__global__ void k_alpha(const float* __restrict__ km, const float* __restrict__ oe,
                        float* __restrict__ alpha) {
  int t = blockIdx.x * 256 + threadIdx.x;
  int r = t >> 4, j = t & 15;
  if (r >= KK) return;
  const float4* p = (const float4*)(km + (size_t)r * EE + j * 8);
  const float4* q = (const float4*)(oe + j * 8);
  float4 a0 = p[0], a1 = p[1], b0 = q[0], b1 = q[1];
  float s = a0.x * b0.x + a0.y * b0.y + a0.z * b0.z + a0.w * b0.w
          + a1.x * b1.x + a1.y * b1.y + a1.z * b1.z + a1.w * b1.w;
  s += __shfl_xor(s, 1); s += __shfl_xor(s, 2);
  s += __shfl_xor(s, 4); s += __shfl_xor(s, 8);
  if (j == 0) alpha[r] = s;
}

// Pack W_hh f32 [1536][512] -> bf16 B_packed[(g*64+cb)*512 + n][8]
// where element j of octet = W_hh[g*512+n][cb*8+j]
__global__ void k_wpack(const float* __restrict__ whh, short* __restrict__ bp) {
  int o = blockIdx.x * 256 + threadIdx.x;  // < 98304
  int n = o & 511;
  int gk = o >> 9;           // g*64+cb, 0..191
  int g = gk >> 6, cb = gk & 63;
  const float* src = whh + ((size_t)(g * 512 + n)) * 512 + cb * 8;
  float4 f0 = *(const float4*)src;
  float4 f1 = *(const float4*)(src + 4);
  bh8 w;
  w[0] = f2b(f0.x); w[1] = f2b(f0.y); w[2] = f2b(f0.z); w[3] = f2b(f0.w);
  w[4] = f2b(f1.x); w[5] = f2b(f1.y); w[6] = f2b(f1.z); w[7] = f2b(f1.w);
  *(bh8*)(bp + (size_t)o * 8) = w;
}

// gix[j] = dot(W_ih[j,:], concat(ex_e, s)) ; one wave per output. Also zero hkp.
__global__ void k_gix(const float* __restrict__ wih, const float* __restrict__ exe,
                      const float* __restrict__ sv, float* __restrict__ gix,
                      float* __restrict__ hkp) {
  int t = threadIdx.x;
  if (blockIdx.x < 2) {
    int g = blockIdx.x * 256 + t;
    hkp[g] = 0.f;
  }
  int w = blockIdx.x * 4 + (t >> 6);
  int lane = t & 63;
  float s1 = sv[0];
  float sum = 0.f;
  for (int d = lane; d < DIN; d += 64) {
    float xv = (d < 512) ? exe[d] : s1;
    sum += wih[(size_t)w * DIN + d] * xv;
  }
  sum += __shfl_xor(sum, 1); sum += __shfl_xor(sum, 2);
  sum += __shfl_xor(sum, 4); sum += __shfl_xor(sum, 8);
  sum += __shfl_xor(sum, 16); sum += __shfl_xor(sum, 32);
  if (lane == 0) gix[w] = sum;
}

// single-block softmax over alpha[50000] -> beta
__global__ void k_softmax(const float* __restrict__ alpha, float* __restrict__ beta) {
  __shared__ float red[16];
  __shared__ float stat[2];
  int t = threadIdx.x;  // 1024
  float m = -1e30f;
  for (int i = t; i < KK; i += 1024) m = fmaxf(m, alpha[i]);
  for (int o = 1; o < 64; o <<= 1) m = fmaxf(m, __shfl_xor(m, o));
  if ((t & 63) == 0) red[t >> 6] = m;
  __syncthreads();
  if (t == 0) {
    float mm = red[0];
    for (int i = 1; i < 16; ++i) mm = fmaxf(mm, red[i]);
    stat[0] = mm;
  }
  __syncthreads();
  float Mx = stat[0];
  float ss = 0.f;
  for (int i = t; i < KK; i += 1024) ss += __expf(alpha[i] - Mx);
  for (int o = 1; o < 64; o <<= 1) ss += __shfl_xor(ss, o);
  if ((t & 63) == 0) red[t >> 6] = ss;
  __syncthreads();
  if (t == 0) {
    float tot = 0.f;
    for (int i = 0; i < 16; ++i) tot += red[i];
    stat[1] = tot;
  }
  __syncthreads();
  float inv = 1.f / stat[1];
  for (int i = t; i < KK; i += 1024) beta[i] = __expf(alpha[i] - Mx) * inv;
}

// Fused: h->bf16 LDS staging (+hkp partials), gh = h @ W_hh^T via MFMA, GRU gates, h_new
// BM=128 rows/block, 8 waves (2m x 4n), wave tile 64x32, mfma_f32_32x32x16_bf16
// A LDS layout: [cb 0..63][row 0..127][8], slab stride 1040 shorts (pad 16)
__global__ __launch_bounds__(512, 2) void k_gemm(
    const float* __restrict__ h, const float* __restrict__ beta,
    const float* __restrict__ gix, const float* __restrict__ b_ih,
    const float* __restrict__ b_hh, const short* __restrict__ bp,
    float* __restrict__ hkp, float* __restrict__ out) {
  __shared__ short Abuf[64 * 1040];
  __shared__ float hk[512];
  const int t = threadIdx.x;
  const int r0 = blockIdx.x * 128;
  hk[t] = 0.f;

  const int kb = t & 63;   // column-octet (c>>3)
  const int wid = t >> 6;  // wave id 0..7
  float hp[8] = {0.f, 0.f, 0.f, 0.f, 0.f, 0.f, 0.f, 0.f};
  #pragma unroll 2
  for (int pass = 0; pass < 16; ++pass) {
    const int r = pass * 8 + wid;
    const int gr = r0 + r;
    float v[8];
    float bv = 0.f;
    if (gr < KK) {
      const float4* p = (const float4*)(h + (size_t)gr * HH + kb * 8);
      float4 x0 = p[0], x1 = p[1];
      v[0] = x0.x; v[1] = x0.y; v[2] = x0.z; v[3] = x0.w;
      v[4] = x1.x; v[5] = x1.y; v[6] = x1.z; v[7] = x1.w;
      bv = beta[gr];
    } else {
      #pragma unroll
      for (int j = 0; j < 8; ++j) v[j] = 0.f;
    }
    bh8 w;
    #pragma unroll
    for (int j = 0; j < 8; ++j) { hp[j] += bv * v[j]; w[j] = f2b(v[j]); }
    *(bh8*)&Abuf[kb * 1040 + r * 8] = w;
  }
  __syncthreads();
  #pragma unroll
  for (int j = 0; j < 8; ++j) atomicAdd(&hk[kb * 8 + j], hp[j]);
  __syncthreads();
  atomicAdd(&hkp[t], hk[t]);

  const int lane = t & 63;
  const int l31 = lane & 31;
  const int lh = lane >> 5;
  const int wm = wid >> 2;  // 0..1
  const int wn = wid & 3;   // 0..3
  const int abase = lh * 1040 + (wm * 64 + l31) * 8;
  float* out1 = out + 1;

  for (int ni = 0; ni < 4; ++ni) {
    const int col = ni * 128 + wn * 32 + l31;
    const short* bpc = bp + ((size_t)(lh * 512 + col)) * 8;
    fx16 acc[2][3];
    #pragma unroll
    for (int mi = 0; mi < 2; ++mi)
      #pragma unroll
      for (int g = 0; g < 3; ++g)
        #pragma unroll
        for (int q = 0; q < 16; ++q) acc[mi][g][q] = 0.f;

    bh8 bA[3], bB[3];
    auto LDB = [&](bh8* d, int s) {
      d[0] = *(const bh8*)(bpc + (size_t)s * 8192);
      d[1] = *(const bh8*)(bpc + 262144 + (size_t)s * 8192);
      d[2] = *(const bh8*)(bpc + 524288 + (size_t)s * 8192);
    };
    LDB(bA, 0);
    #pragma unroll 4
    for (int s2 = 0; s2 < 16; ++s2) {
      const int s0 = 2 * s2, s1 = 2 * s2 + 1;
      LDB(bB, s1);
      bh8 a0 = *(const bh8*)&Abuf[abase + s0 * 2080];
      bh8 a1 = *(const bh8*)&Abuf[abase + s0 * 2080 + 256];
      acc[0][0] = __builtin_amdgcn_mfma_f32_32x32x16_bf16(a0, bA[0], acc[0][0], 0, 0, 0);
      acc[0][1] = __builtin_amdgcn_mfma_f32_32x32x16_bf16(a0, bA[1], acc[0][1], 0, 0, 0);
      acc[0][2] = __builtin_amdgcn_mfma_f32_32x32x16_bf16(a0, bA[2], acc[0][2], 0, 0, 0);
      acc[1][0] = __builtin_amdgcn_mfma_f32_32x32x16_bf16(a1, bA[0], acc[1][0], 0, 0, 0);
      acc[1][1] = __builtin_amdgcn_mfma_f32_32x32x16_bf16(a1, bA[1], acc[1][1], 0, 0, 0);
      acc[1][2] = __builtin_amdgcn_mfma_f32_32x32x16_bf16(a1, bA[2], acc[1][2], 0, 0, 0);
      if (s2 < 15) LDB(bA, s0 + 2);
      a0 = *(const bh8*)&Abuf[abase + s1 * 2080];
      a1 = *(const bh8*)&Abuf[abase + s1 * 2080 + 256];
      acc[0][0] = __builtin_amdgcn_mfma_f32_32x32x16_bf16(a0, bB[0], acc[0][0], 0, 0, 0);
      acc[0][1] = __builtin_amdgcn_mfma_f32_32x32x16_bf16(a0, bB[1], acc[0][1], 0, 0, 0);
      acc[0][2] = __builtin_amdgcn_mfma_f32_32x32x16_bf16(a0, bB[2], acc[0][2], 0, 0, 0);
      acc[1][0] = __builtin_amdgcn_mfma_f32_32x32x16_bf16(a1, bB[0], acc[1][0], 0, 0, 0);
      acc[1][1] = __builtin_amdgcn_mfma_f32_32x32x16_bf16(a1, bB[1], acc[1][1], 0, 0, 0);
      acc[1][2] = __builtin_amdgcn_mfma_f32_32x32x16_bf16(a1, bB[2], acc[1][2], 0, 0, 0);
    }

    // epilogue: gates + h_new
    const int cb = col >> 3, c7 = col & 7;
    const float gxr = gix[col], gxz = gix[col + 512], gxn = gix[col + 1024];
    const float bir = b_ih[col], biz = b_ih[col + 512], bin = b_ih[col + 1024];
    const float bhr = b_hh[col], bhz = b_hh[col + 512], bhn = b_hh[col + 1024];
    #pragma unroll
    for (int mi = 0; mi < 2; ++mi) {
      const int lrb = wm * 64 + mi * 32 + 4 * lh;
      #pragma unroll
      for (int q = 0; q < 16; ++q) {
        const int lr = lrb + (q & 3) + 8 * (q >> 2);
        const int gr = r0 + lr;
        if (gr < KK) {
          const float bv = beta[gr];
          const float rv = sigm(acc[mi][0][q] + bv * gxr + bir + bhr);
          const float zv = sigm(acc[mi][1][q] + bv * gxz + biz + bhz);
          const float nv = tanh_(bv * gxn + bin + rv * (acc[mi][2][q] + bhn));
          const float ho = b2f(Abuf[cb * 1040 + lr * 8 + c7]);
          out1[(size_t)gr * HH + col] = (1.f - zv) * nv + zv * ho;
        }
      }
    }
  }
}

// predict_score = score_W[0:512].ex_e + score_W[512:1024].hkp + score_b
__global__ void k_score(const float* __restrict__ sw, const float* __restrict__ sb,
                        const float* __restrict__ exe, const float* __restrict__ hkp,
                        float* __restrict__ out) {
  __shared__ float red[8];
  int t = threadIdx.x;  // 512
  float v = sw[t] * exe[t] + sw[512 + t] * hkp[t];
  for (int o = 1; o < 64; o <<= 1) v += __shfl_xor(v, o);
  if ((t & 63) == 0) red[t >> 6] = v;
  __syncthreads();
  if (t == 0) {
    float s = sb[0];
    for (int i = 0; i < 8; ++i) s += red[i];
    out[0] = s;
  }
}

extern "C" void kernel_launch(void* const* d_in, const int* in_sizes, int n_in,
                              void* d_out, int out_size, void* d_ws, size_t ws_size,
                              hipStream_t stream) {
  const float* o_e  = (const float*)d_in[0];
  const float* ex_e = (const float*)d_in[1];
  const float* s    = (const float*)d_in[2];
  const float* h    = (const float*)d_in[3];
  const float* km   = (const float*)d_in[4];
  const float* W_ih = (const float*)d_in[5];
  const float* W_hh = (const float*)d_in[6];
  const float* b_ih = (const float*)d_in[7];
  const float* b_hh = (const float*)d_in[8];
  const float* sW   = (const float*)d_in[9];
  const float* sb   = (const float*)d_in[10];
  float* out = (float*)d_out;

  float* wsf   = (float*)d_ws;
  float* alpha = wsf;            // 50000
  float* beta  = wsf + 50048;    // 50000
  float* gix   = wsf + 100096;   // 1536
  float* hkp   = wsf + 101632;   // 512
  short* bp    = (short*)(wsf + 102400);  // 1,572,864 B

  k_alpha<<<3125, 256, 0, stream>>>(km, o_e, alpha);
  k_wpack<<<384, 256, 0, stream>>>(W_hh, bp);
  k_gix<<<384, 256, 0, stream>>>(W_ih, ex_e, s, gix, hkp);
  k_softmax<<<1, 1024, 0, stream>>>(alpha, beta);
  k_gemm<<<391, 512, 0, stream>>>(h, beta, gix, b_ih, b_hh, bp, hkp, out);
  k_score<<<1, 512, 0, stream>>>(sW, sb, ex_e, hkp, out);
}